// Round 2
// baseline (10727.860 us; speedup 1.0000x reference)
//
#include <hip/hip_runtime.h>

typedef unsigned short ushort_t;
typedef __attribute__((ext_vector_type(8))) short short8;
typedef __attribute__((ext_vector_type(4))) float floatx4;

#define TT 128
#define UNITS 512
#define EMBED 64
#define PATHN 8192
#define DECE 2048
#define MROWS 8192

__device__ __forceinline__ float bf2f(ushort_t u) {
  union { unsigned int i; float f; } v;
  v.i = ((unsigned int)u) << 16;
  return v.f;
}
__device__ __forceinline__ ushort_t f2bf(float f) {
  union { float f; unsigned int i; } v;
  v.f = f;
  unsigned int x = v.i;
  x += 0x7fffu + ((x >> 16) & 1u);  // RNE
  return (ushort_t)(x >> 16);
}
__device__ __forceinline__ float loadF(const void* p, size_t i, bool f32) {
  return f32 ? ((const float*)p)[i] : bf2f(((const ushort_t*)p)[i]);
}
__device__ __forceinline__ int loadI(const void* p, size_t i, bool i64) {
  return i64 ? (int)((const long long*)p)[i] : ((const int*)p)[i];
}

// mode[0]=1 iff float tensors are fp32 (else bf16); mode[1]=1 iff ints are int64.
__global__ void detect_mode(const void* __restrict__ emb, const void* __restrict__ tgt,
                            int* __restrict__ mode) {
  __shared__ int crazy, nz;
  if (threadIdx.x == 0) { crazy = 0; nz = 0; }
  __syncthreads();
  int c = 0;
  for (int i = threadIdx.x; i < 2048; i += 256) {  // emb has >=3520 elems either way
    ushort_t u = ((const ushort_t*)emb)[i];
    int e = (u >> 7) & 0xff;
    if (e > 0x90) c++;  // |v|>~1e5: impossible for 0.02-scale bf16 weights
  }
  if (c) atomicAdd(&crazy, c);
  if (threadIdx.x < 32) {
    int v = ((const int*)tgt)[threadIdx.x * 2 + 1];  // odd halves of first 32 int64s
    if (v != 0) atomicAdd(&nz, 1);
  }
  __syncthreads();
  if (threadIdx.x == 0) {
    mode[0] = (crazy > 16) ? 1 : 0;
    mode[1] = (nz == 0) ? 1 : 0;
  }
}

__global__ void gather_enc(const int* __restrict__ mode, const void* __restrict__ inputs,
                           const void* __restrict__ emb, ushort_t* __restrict__ out) {
  const bool f32 = mode[0] != 0, i64 = mode[1] != 0;
  int tid = blockIdx.x * blockDim.x + threadIdx.x;  // 8192*8
  int m = tid >> 3, part = tid & 7;
  int b = m & 63, t = m >> 6;
  int ch = loadI(inputs, (size_t)b * TT + t, i64);
  size_t src = (size_t)ch * EMBED + part * 8;
  ushort_t tmp[8];
  if (f32) {
#pragma unroll
    for (int j = 0; j < 8; j++) tmp[j] = f2bf(((const float*)emb)[src + j]);
  } else {
    *(short8*)tmp = *(const short8*)((const ushort_t*)emb + src);
  }
  *(short8*)(out + (size_t)m * EMBED + part * 8) = *(short8*)tmp;
}

__global__ void gather_dec(const int* __restrict__ mode, const void* __restrict__ targets,
                           const void* __restrict__ emb, ushort_t* __restrict__ out) {
  const bool f32 = mode[0] != 0, i64 = mode[1] != 0;
  int tid = blockIdx.x * blockDim.x + threadIdx.x;  // 8192*256
  int m = tid >> 8, part = tid & 255;
  int b = m & 63, t = m >> 6;
  int p = loadI(targets, (size_t)b * TT + t, i64);
  size_t src = (size_t)p * DECE + part * 8;
  ushort_t tmp[8];
  if (f32) {
#pragma unroll
    for (int j = 0; j < 8; j++) tmp[j] = f2bf(((const float*)emb)[src + j]);
  } else {
    *(short8*)tmp = *(const short8*)((const ushort_t*)emb + src);
  }
  *(short8*)(out + (size_t)m * DECE + part * 8) = *(short8*)tmp;
}

// transpose harness [R,C] (element offset eo) -> internal bf16 [C,R]
__global__ void transpose_elems(const int* __restrict__ mode, const void* __restrict__ in,
                                size_t eo, ushort_t* __restrict__ out, int R, int C) {
  const bool f32 = mode[0] != 0;
  __shared__ ushort_t tl[32][33];
  int c0 = blockIdx.x * 32, r0 = blockIdx.y * 32;
  int x = threadIdx.x & 31, y4 = threadIdx.x >> 5;  // 256 threads
#pragma unroll
  for (int i = 0; i < 4; i++) {
    int y = y4 + i * 8;
    tl[y][x] = f2bf(loadF(in, eo + (size_t)(r0 + y) * C + (c0 + x), f32));
  }
  __syncthreads();
#pragma unroll
  for (int i = 0; i < 4; i++) {
    int y = y4 + i * 8;
    out[(size_t)(c0 + y) * R + (r0 + x)] = tl[x][y];
  }
}

// MFMA GEMM: C = act(A[M,K] @ Bt[N,K]^T + bias). A/Bt internal bf16.
// bias harness dtype. Output bf16 internal, or TSTORE -> d_out (harness dtype,
// rows m=t*64+b stored as out[b][t][n]).
template <int RELU, int BIAS, int TSTORE>
__global__ __launch_bounds__(256) void gemm_bt(const int* __restrict__ mode,
                                               const ushort_t* __restrict__ A,
                                               const ushort_t* __restrict__ Bt,
                                               const void* __restrict__ bias,
                                               void* __restrict__ Cp, int M, int N, int K) {
  const bool f32 = mode[0] != 0;
  __shared__ __align__(16) ushort_t As[128 * 40];
  __shared__ __align__(16) ushort_t Bs[128 * 40];
  const int tid = threadIdx.x;
  const int lane = tid & 63, wv = tid >> 6;
  const int quad = lane >> 4, l16 = lane & 15;
  const int wrow = (wv & 1) * 64, wcol = (wv >> 1) * 64;
  floatx4 acc[4][4] = {};
  const int srow = tid >> 1, scol = (tid & 1) * 16;
  const ushort_t* Ag = A + (size_t)(blockIdx.y * 128 + srow) * K + scol;
  const ushort_t* Bg = Bt + (size_t)(blockIdx.x * 128 + srow) * K + scol;
  ushort_t* AsW = &As[srow * 40 + scol];
  ushort_t* BsW = &Bs[srow * 40 + scol];
  for (int k0 = 0; k0 < K; k0 += 32) {
    short8 a0 = *(const short8*)(Ag + k0);
    short8 a1 = *(const short8*)(Ag + k0 + 8);
    short8 b0 = *(const short8*)(Bg + k0);
    short8 b1 = *(const short8*)(Bg + k0 + 8);
    __syncthreads();
    *(short8*)AsW = a0;
    *(short8*)(AsW + 8) = a1;
    *(short8*)BsW = b0;
    *(short8*)(BsW + 8) = b1;
    __syncthreads();
    short8 af[4], bfr[4];
#pragma unroll
    for (int i = 0; i < 4; i++) af[i] = *(const short8*)&As[(wrow + i * 16 + l16) * 40 + quad * 8];
#pragma unroll
    for (int j = 0; j < 4; j++) bfr[j] = *(const short8*)&Bs[(wcol + j * 16 + l16) * 40 + quad * 8];
#pragma unroll
    for (int i = 0; i < 4; i++)
#pragma unroll
      for (int j = 0; j < 4; j++)
        acc[i][j] = __builtin_amdgcn_mfma_f32_16x16x32_bf16(af[i], bfr[j], acc[i][j], 0, 0, 0);
  }
  const int mbase = blockIdx.y * 128 + wrow;
  const int nbase = blockIdx.x * 128 + wcol;
#pragma unroll
  for (int j = 0; j < 4; j++) {
    int col = nbase + j * 16 + l16;
    float bv = BIAS ? loadF(bias, col, f32) : 0.0f;
#pragma unroll
    for (int i = 0; i < 4; i++) {
#pragma unroll
      for (int r = 0; r < 4; r++) {
        int row = mbase + i * 16 + quad * 4 + r;  // D: col=lane&15, row=quad*4+reg (m89/m91)
        float v = acc[i][j][r] + bv;
        if (RELU) v = fmaxf(v, 0.0f);
        if (TSTORE) {
          size_t o = (size_t)(row & 63) * ((size_t)TT * PATHN) + (size_t)(row >> 6) * PATHN + col;
          if (f32) ((float*)Cp)[o] = v;
          else ((ushort_t*)Cp)[o] = f2bf(v);
        } else {
          ((ushort_t*)Cp)[(size_t)row * N + col] = f2bf(v);
        }
      }
    }
  }
}

// One (T, layer) LSTM cell step. T in [0,256): enc T<128, dec T>=128 (t=T-128).
// 128 one-wave WGs: rb=bx>>5 (16 batch rows), cb=bx&31 (16 unit cols x 4 gates).
// h ping-pong on T parity; l>0 x-input = h_{l-1} of same T (earlier launch, parity pw).
__global__ __launch_bounds__(64) void lstm_step(
    const int* __restrict__ mode, int T, int l, const ushort_t* __restrict__ z1,
    const ushort_t* __restrict__ Wxt, const ushort_t* __restrict__ Wht,
    const void* __restrict__ bias, int boff, ushort_t* __restrict__ hbuf,
    float* __restrict__ cbuf, ushort_t* __restrict__ decouts) {
  const bool f32 = mode[0] != 0;
  const int t = (T < TT) ? T : T - TT;
  const int lane = threadIdx.x;
  const int quad = lane >> 4, l16 = lane & 15;
  const int rb = blockIdx.x >> 5, cb = blockIdx.x & 31;
  const int pw = T & 1, pr = pw ^ 1;
  const ushort_t* hL = hbuf + ((size_t)pr * 3 + l) * 64 * 512;  // h_l(t-1)
  ushort_t* hO = hbuf + ((size_t)pw * 3 + l) * 64 * 512;
  floatx4 acc[4] = {};
  const int arow = rb * 16 + l16;
  const int koff = quad * 8;
  if (l > 0) {
    const ushort_t* hX = hbuf + ((size_t)pw * 3 + (l - 1)) * 64 * 512;  // h_{l-1}(t)
#pragma unroll 4
    for (int k0 = 0; k0 < 512; k0 += 32) {
      short8 a = *(const short8*)&hX[arow * 512 + k0 + koff];
#pragma unroll
      for (int g = 0; g < 4; g++) {
        short8 b = *(const short8*)&Wxt[(size_t)(g * 512 + cb * 16 + l16) * 512 + k0 + koff];
        acc[g] = __builtin_amdgcn_mfma_f32_16x16x32_bf16(a, b, acc[g], 0, 0, 0);
      }
    }
  }
#pragma unroll 4
  for (int k0 = 0; k0 < 512; k0 += 32) {
    short8 a = *(const short8*)&hL[arow * 512 + k0 + koff];
#pragma unroll
    for (int g = 0; g < 4; g++) {
      short8 b = *(const short8*)&Wht[(size_t)(g * 512 + cb * 16 + l16) * 512 + k0 + koff];
      acc[g] = __builtin_amdgcn_mfma_f32_16x16x32_bf16(a, b, acc[g], 0, 0, 0);
    }
  }
  const int col = cb * 16 + l16;
  float bi = loadF(bias, boff + col, f32);
  float bff = loadF(bias, boff + 512 + col, f32);
  float bg = loadF(bias, boff + 1024 + col, f32);
  float bo = loadF(bias, boff + 1536 + col, f32);
#pragma unroll
  for (int r = 0; r < 4; r++) {
    int row = rb * 16 + quad * 4 + r;
    float zi = acc[0][r] + bi;
    float zf = acc[1][r] + bff;
    float zg = acc[2][r] + bg;
    float zo = acc[3][r] + bo;
    if (l == 0) {
      const ushort_t* zr = z1 + ((size_t)t * 64 + row) * 2048;
      zi += bf2f(zr[col]);
      zf += bf2f(zr[512 + col]);
      zg += bf2f(zr[1024 + col]);
      zo += bf2f(zr[1536 + col]);
    }
    zi = fminf(fmaxf(zi, -30.f), 30.f);  // NaN/overflow guard
    zf = fminf(fmaxf(zf, -30.f), 30.f);
    zg = fminf(fmaxf(zg, -30.f), 30.f);
    zo = fminf(fmaxf(zo, -30.f), 30.f);
    float iv = 1.0f / (1.0f + expf(-zi));
    float fv = 1.0f / (1.0f + expf(-zf));
    float gv = tanhf(zg);
    float ov = 1.0f / (1.0f + expf(-zo));
    size_t ci = ((size_t)l * 64 + row) * 512 + col;
    float cn = fv * cbuf[ci] + iv * gv;
    cbuf[ci] = cn;
    float hv = ov * tanhf(cn);
    hO[(size_t)row * 512 + col] = f2bf(hv);
    if (decouts) decouts[((size_t)t * 64 + row) * 512 + col] = f2bf(hv);
  }
}

extern "C" void kernel_launch(void* const* d_in, const int* in_sizes, int n_in, void* d_out,
                              int out_size, void* d_ws, size_t ws_size, hipStream_t stream) {
  const void* inputs = d_in[0];
  const void* targets = d_in[1];
  const void* input_embed = d_in[2];
  const void* enc_Wd = d_in[3];
  const void* enc_bd = d_in[4];
  const void* enc_Wx = d_in[5];
  const void* enc_Wh = d_in[6];
  const void* enc_b = d_in[7];
  const void* dec_embed = d_in[8];
  const void* dec_Wd = d_in[9];
  const void* dec_bd = d_in[10];
  const void* dec_Wx = d_in[11];
  const void* dec_Wh = d_in[12];
  const void* dec_b = d_in[13];
  const void* out_W1 = d_in[14];
  const void* out_b1 = d_in[15];
  const void* out_W2 = d_in[16];
  const void* out_b2 = d_in[17];

  char* ws = (char*)d_ws;
  size_t off = 0;
  auto alloc = [&](size_t bytes) {
    void* p = ws + off;
    off += (bytes + 255) & ~(size_t)255;
    return p;
  };
  int* mode = (int*)alloc(256);
  ushort_t* encWd_t = (ushort_t*)alloc((size_t)512 * 64 * 2);
  ushort_t* encWx_t = (ushort_t*)alloc((size_t)3 * 2048 * 512 * 2);
  ushort_t* encWh_t = (ushort_t*)alloc((size_t)3 * 2048 * 512 * 2);
  ushort_t* decWd_t = (ushort_t*)alloc((size_t)512 * 2048 * 2);
  ushort_t* decWx_t = (ushort_t*)alloc((size_t)3 * 2048 * 512 * 2);
  ushort_t* decWh_t = (ushort_t*)alloc((size_t)3 * 2048 * 512 * 2);
  ushort_t* outW1_t = (ushort_t*)alloc((size_t)2048 * 512 * 2);
  ushort_t* encx = (ushort_t*)alloc((size_t)MROWS * EMBED * 2);
  ushort_t* encin = (ushort_t*)alloc((size_t)MROWS * 512 * 2);
  ushort_t* dect = (ushort_t*)alloc((size_t)MROWS * 2048 * 2);  // reused as out_W2^T
  ushort_t* decin = (ushort_t*)alloc((size_t)MROWS * 512 * 2);
  ushort_t* zbuf = (ushort_t*)alloc((size_t)MROWS * 2048 * 2);  // layer0 pre-acts
  ushort_t* hbuf = (ushort_t*)alloc((size_t)2 * 3 * 64 * 512 * 2);
  float* cbuf = (float*)alloc((size_t)3 * 64 * 512 * 4);
  ushort_t* decouts = (ushort_t*)alloc((size_t)MROWS * 512 * 2);
  ushort_t* h1 = (ushort_t*)alloc((size_t)MROWS * 2048 * 2);
  ushort_t* W2t = dect;

  hipMemsetAsync(hbuf, 0, (size_t)2 * 3 * 64 * 512 * 2, stream);
  hipMemsetAsync(cbuf, 0, (size_t)3 * 64 * 512 * 4, stream);

  detect_mode<<<1, 256, 0, stream>>>(input_embed, targets, mode);

  gather_enc<<<256, 256, 0, stream>>>(mode, inputs, input_embed, encx);
  gather_dec<<<8192, 256, 0, stream>>>(mode, targets, dec_embed, dect);

  transpose_elems<<<dim3(16, 2), 256, 0, stream>>>(mode, enc_Wd, 0, encWd_t, 64, 512);
  for (int l = 0; l < 3; l++) {
    size_t eo = (size_t)l * 512 * 2048;  // element offset of layer l in [3,512,2048]
    size_t to = (size_t)l * 2048 * 512;
    transpose_elems<<<dim3(64, 16), 256, 0, stream>>>(mode, enc_Wx, eo, encWx_t + to, 512, 2048);
    transpose_elems<<<dim3(64, 16), 256, 0, stream>>>(mode, enc_Wh, eo, encWh_t + to, 512, 2048);
    transpose_elems<<<dim3(64, 16), 256, 0, stream>>>(mode, dec_Wx, eo, decWx_t + to, 512, 2048);
    transpose_elems<<<dim3(64, 16), 256, 0, stream>>>(mode, dec_Wh, eo, decWh_t + to, 512, 2048);
  }
  transpose_elems<<<dim3(16, 64), 256, 0, stream>>>(mode, dec_Wd, 0, decWd_t, 2048, 512);
  transpose_elems<<<dim3(64, 16), 256, 0, stream>>>(mode, out_W1, 0, outW1_t, 512, 2048);

  // enc dense -> encin; enc layer0 pre-acts -> zbuf; dec dense -> decin
  gemm_bt<1, 1, 0><<<dim3(4, 64), 256, 0, stream>>>(mode, encx, encWd_t, enc_bd, encin, MROWS, 512, 64);
  gemm_bt<0, 0, 0><<<dim3(16, 64), 256, 0, stream>>>(mode, encin, encWx_t, nullptr, zbuf, MROWS, 2048, 512);
  gemm_bt<1, 1, 0><<<dim3(4, 64), 256, 0, stream>>>(mode, dect, decWd_t, dec_bd, decin, MROWS, 512, 2048);
  transpose_elems<<<dim3(256, 64), 256, 0, stream>>>(mode, out_W2, 0, W2t, 2048, 8192);

  for (int T = 0; T < 128; ++T)
    for (int l = 0; l < 3; ++l)
      lstm_step<<<128, 64, 0, stream>>>(mode, T, l, zbuf, encWx_t + (size_t)l * 2048 * 512,
                                        encWh_t + (size_t)l * 2048 * 512, enc_b, l * 2048, hbuf,
                                        cbuf, nullptr);
  gemm_bt<0, 0, 0><<<dim3(16, 64), 256, 0, stream>>>(mode, decin, decWx_t, nullptr, zbuf, MROWS, 2048, 512);
  for (int T = 128; T < 256; ++T)
    for (int l = 0; l < 3; ++l)
      lstm_step<<<128, 64, 0, stream>>>(mode, T, l, zbuf, decWx_t + (size_t)l * 2048 * 512,
                                        decWh_t + (size_t)l * 2048 * 512, dec_b, l * 2048, hbuf,
                                        cbuf, (l == 2) ? decouts : nullptr);

  gemm_bt<1, 1, 0><<<dim3(16, 64), 256, 0, stream>>>(mode, decouts, outW1_t, out_b1, h1, MROWS, 2048, 512);
  gemm_bt<1, 1, 1><<<dim3(64, 64), 256, 0, stream>>>(mode, h1, W2t, out_b2, d_out, MROWS, PATHN, 2048);
}